// Round 1
// baseline (13560.747 us; speedup 1.0000x reference)
//
#include <hip/hip_runtime.h>
#include <math.h>

constexpr int kT = 512;
constexpr int kB = 64;
constexpr int kC = 1024;
constexpr int kD = 512;
constexpr int kN3 = 1536;

typedef __attribute__((ext_vector_type(8))) short bf16x8;
typedef __attribute__((ext_vector_type(4))) float f32x4;
typedef __attribute__((ext_vector_type(4))) unsigned int u32x4;

__device__ __forceinline__ float b2f(unsigned short u) {
  unsigned int v = ((unsigned int)u) << 16;
  return __builtin_bit_cast(float, v);
}
__device__ __forceinline__ unsigned short f2b(float f) {
  unsigned int u = __builtin_bit_cast(unsigned int, f);
  u += 0x7fffu + ((u >> 16) & 1u);
  return (unsigned short)(u >> 16);
}
__device__ __forceinline__ float sigm(float x) {
  x = fminf(15.f, fmaxf(-15.f, x));
  return 1.f / (1.f + __expf(-x));
}
__device__ __forceinline__ float tanh_(float x) {
  x = fminf(15.f, fmaxf(-15.f, x));
  float e2 = __expf(2.f * x);
  return (e2 - 1.f) / (e2 + 1.f);
}
__device__ __forceinline__ float efun(float s) {
  // exp(CLAMP*0.636*atan(s/CLAMP)), CLAMP=5
  return __expf((5.0f * 0.636f) * atanf(s * 0.2f));
}

#define GRIDBAR(NB)                                                                      \
  do {                                                                                   \
    ++gen;                                                                               \
    __syncthreads();                                                                     \
    if (tid == 0) {                                                                      \
      __threadfence();                                                                   \
      int a_ = __hip_atomic_fetch_add(barcnt, 1, __ATOMIC_RELAXED,                       \
                                      __HIP_MEMORY_SCOPE_AGENT);                         \
      if (a_ == (NB)-1) {                                                                \
        __hip_atomic_store(barcnt, 0, __ATOMIC_RELAXED, __HIP_MEMORY_SCOPE_AGENT);       \
        __hip_atomic_store(bargen, gen, __ATOMIC_RELEASE, __HIP_MEMORY_SCOPE_AGENT);     \
      } else {                                                                           \
        while (__hip_atomic_load(bargen, __ATOMIC_ACQUIRE, __HIP_MEMORY_SCOPE_AGENT) <   \
               gen)                                                                      \
          __builtin_amdgcn_s_sleep(4);                                                   \
      }                                                                                  \
      __threadfence();                                                                   \
    }                                                                                    \
    __syncthreads();                                                                     \
  } while (0)

// C[r][n] = sum_k A[r][k]*W[n][k] + bias[n];  M = T*B (r = t*64+b), K=512, N=1536
// AMODE 0: A = x[:, :, D:] fp32 (row r -> x[b, t, D:])   AMODE 1: A = bf16 [r][512]
template <int AMODE>
__global__ __launch_bounds__(256) void gemm_gi_kernel(
    const float* __restrict__ xsrc, const unsigned short* __restrict__ abf,
    const float* __restrict__ W, const float* __restrict__ bias,
    unsigned short* __restrict__ giout) {
  __shared__ __attribute__((aligned(16))) unsigned short As[64][40];
  __shared__ __attribute__((aligned(16))) unsigned short Bs[64][40];
  const int tid = threadIdx.x;
  const int w = tid >> 6, l = tid & 63;
  const int q = l & 15, kg = l >> 4;
  const int bn = blockIdx.x;  // 0..23 (fast dim -> A-tile reuse in L2)
  const int bm = blockIdx.y;  // 0..511
  const int wr = (w >> 1) * 32, wc = (w & 1) * 32;
  f32x4 acc00 = {0.f, 0.f, 0.f, 0.f}, acc01 = {0.f, 0.f, 0.f, 0.f};
  f32x4 acc10 = {0.f, 0.f, 0.f, 0.f}, acc11 = {0.f, 0.f, 0.f, 0.f};
  const int srow = tid >> 2;
  const int sseg = (tid & 3) * 8;
  const int rg_ = bm * 64 + srow;
  const int ng_ = bn * 64 + srow;
  const float* wp = W + (size_t)ng_ * kD + sseg;
  const float* apf = nullptr;
  const unsigned short* apb = nullptr;
  if constexpr (AMODE == 0) {
    const int t = rg_ >> 6, b = rg_ & 63;
    apf = xsrc + (size_t)b * (kT * kC) + (size_t)t * kC + kD + sseg;
  } else {
    apb = abf + (size_t)rg_ * kD + sseg;
  }
  for (int k0 = 0; k0 < kD; k0 += 32) {
    if constexpr (AMODE == 0) {
#pragma unroll
      for (int j = 0; j < 8; j++) As[srow][sseg + j] = f2b(apf[k0 + j]);
    } else {
#pragma unroll
      for (int j = 0; j < 8; j++) As[srow][sseg + j] = apb[k0 + j];
    }
#pragma unroll
    for (int j = 0; j < 8; j++) Bs[srow][sseg + j] = f2b(wp[k0 + j]);
    __syncthreads();
    bf16x8 a0 = *(const bf16x8*)&As[wr + q][kg * 8];
    bf16x8 a1 = *(const bf16x8*)&As[wr + 16 + q][kg * 8];
    bf16x8 b0 = *(const bf16x8*)&Bs[wc + q][kg * 8];
    bf16x8 b1 = *(const bf16x8*)&Bs[wc + 16 + q][kg * 8];
    acc00 = __builtin_amdgcn_mfma_f32_16x16x32_bf16(a0, b0, acc00, 0, 0, 0);
    acc01 = __builtin_amdgcn_mfma_f32_16x16x32_bf16(a0, b1, acc01, 0, 0, 0);
    acc10 = __builtin_amdgcn_mfma_f32_16x16x32_bf16(a1, b0, acc10, 0, 0, 0);
    acc11 = __builtin_amdgcn_mfma_f32_16x16x32_bf16(a1, b1, acc11, 0, 0, 0);
    __syncthreads();
  }
  const int colbase = bn * 64 + wc;
  const float bv0 = bias[colbase + q];
  const float bv1 = bias[colbase + 16 + q];
#pragma unroll
  for (int r = 0; r < 4; r++) {
    const int row0 = bm * 64 + wr + kg * 4 + r;
    const int row1 = row0 + 16;
    giout[(size_t)row0 * kN3 + colbase + q] = f2b(acc00[r] + bv0);
    giout[(size_t)row0 * kN3 + colbase + 16 + q] = f2b(acc01[r] + bv1);
    giout[(size_t)row1 * kN3 + colbase + q] = f2b(acc10[r] + bv0);
    giout[(size_t)row1 * kN3 + colbase + 16 + q] = f2b(acc11[r] + bv1);
  }
}

// Persistent sequential chain. 64 blocks x 256 thr. Block g owns d-slice [8g, 8g+8).
// Per iteration it (1..512), with hprev = state(it-1):
//   P = hprev @ [Whh(r,z,n) | cgW | Wo(s,t)]  (64 x 48 cols, K=512, all in LDS bf16)
//   epilogue: y(it-1) outputs; state(it) = GRU-combine(gi(it), gh(it), hprev)
// M2=0: chain A (h2 / y1 / y1o, writes y1buf + out[:, :, :512])
// M2=1: chain B (h1 / y2 with x2g = x2*e(c1), writes out[:, :, 512:])
template <int M2>
__global__ __launch_bounds__(256) void chain_kernel(
    const float* __restrict__ x, const unsigned short* __restrict__ gi,
    const float* __restrict__ Whh, const float* __restrict__ cgW,
    const float* __restrict__ Wo, const float* __restrict__ bhh,
    const float* __restrict__ cgb, const float* __restrict__ bo,
    unsigned short* __restrict__ y1buf, float* __restrict__ out,
    unsigned short* __restrict__ hbuf, int* __restrict__ barcnt,
    int* __restrict__ bargen) {
  const int g = blockIdx.x;  // 64 blocks
  const int tid = threadIdx.x;
  const int w = tid >> 6;
  const int l = tid & 63;
  const int q = l & 15;
  const int kg = l >> 4;
  const bool lo = (q < 8);
  const int qm = q & 7;
  const int d = 8 * g + qm;
  const int browbase = 16 * w + 4 * kg;

  __shared__ __attribute__((aligned(16))) unsigned short wlds[48 * 512];

  // stage 48 weight rows (bf16, XOR-swizzled 16B chunks to kill bank conflicts)
  for (int c = tid; c < 48 * 64; c += 256) {
    const int u = c >> 6, kb = c & 63;
    const int s8 = 8 * g + (u & 7);
    const int sel = u >> 3;
    const float* wrp = (sel == 0)   ? Whh + (size_t)s8 * kD
                       : (sel == 1) ? Whh + (size_t)(512 + s8) * kD
                       : (sel == 2) ? Whh + (size_t)(1024 + s8) * kD
                       : (sel == 3) ? cgW + (size_t)s8 * kD
                       : (sel == 4) ? Wo + (size_t)s8 * kD
                                    : Wo + (size_t)(512 + s8) * kD;
    const float* p = wrp + kb * 8;
    u32x4 v;
#pragma unroll
    for (int j = 0; j < 4; j++)
      v[j] = (unsigned int)f2b(p[2 * j]) | ((unsigned int)f2b(p[2 * j + 1]) << 16);
    const int byteoff = u * 1024 + ((kb * 16) ^ ((u & 7) << 4));
    *(u32x4*)((char*)wlds + byteoff) = v;
  }

  float biasv[3];
#pragma unroll
  for (int t0 = 0; t0 < 3; t0++) {
    const int v = 16 * t0 + q;
    const int s8 = 8 * g + (v & 7);
    const int sel = v >> 3;
    biasv[t0] = (sel == 0)   ? bhh[s8]
                : (sel == 1) ? bhh[512 + s8]
                : (sel == 2) ? bhh[1024 + s8]
                : (sel == 3) ? cgb[s8]
                : (sel == 4) ? bo[s8]
                             : bo[512 + s8];
  }

  float hsl[4] = {0.f, 0.f, 0.f, 0.f};
  float ecp[4];
#pragma unroll
  for (int r = 0; r < 4; r++) ecp[r] = efun(cgb[d]);  // e(c(0)) (h=0 -> bias only)

  if (lo) {  // state(0) = combine(gi(0), bhh, h=0)
#pragma unroll
    for (int r = 0; r < 4; r++) {
      const int b = browbase + r;
      const unsigned short* gp = gi + (size_t)b * kN3 + d;
      const float rr = sigm(b2f(gp[0]) + bhh[d]);
      const float zz = sigm(b2f(gp[512]) + bhh[512 + d]);
      const float nn = tanh_(b2f(gp[1024]) + rr * bhh[1024 + d]);
      const float h0 = (1.f - zz) * nn;
      hsl[r] = h0;
      hbuf[(size_t)b * 512 + d] = f2b(h0);
    }
  }

  int gen = 0;
  GRIDBAR(64);

#pragma unroll 1
  for (int it = 1; it <= kT; ++it) {
    const unsigned short* hprev = hbuf + (size_t)((it - 1) & 1) * (kB * 512);
    const unsigned short* ap = hprev + (size_t)(16 * w + q) * 512 + kg * 8;
    bf16x8 afr[16];
#pragma unroll
    for (int kk = 0; kk < 16; kk++) afr[kk] = *(const bf16x8*)(ap + kk * 32);
    f32x4 acc0 = {0.f, 0.f, 0.f, 0.f};
    f32x4 acc1 = {0.f, 0.f, 0.f, 0.f};
    f32x4 acc2 = {0.f, 0.f, 0.f, 0.f};
    const int sw = (q & 7) << 4;
#pragma unroll
    for (int kk = 0; kk < 16; kk++) {
      const int kbyte = (kk * 32 + kg * 8) * 2;
      bf16x8 b0 = *(const bf16x8*)((const char*)wlds + q * 1024 + (kbyte ^ sw));
      bf16x8 b1 = *(const bf16x8*)((const char*)wlds + (16 + q) * 1024 + (kbyte ^ sw));
      bf16x8 b2 = *(const bf16x8*)((const char*)wlds + (32 + q) * 1024 + (kbyte ^ sw));
      acc0 = __builtin_amdgcn_mfma_f32_16x16x32_bf16(afr[kk], b0, acc0, 0, 0, 0);
      acc1 = __builtin_amdgcn_mfma_f32_16x16x32_bf16(afr[kk], b1, acc1, 0, 0, 0);
      acc2 = __builtin_amdgcn_mfma_f32_16x16x32_bf16(afr[kk], b2, acc2, 0, 0, 0);
    }
    float ab0[4], ab1[4], ab2[4];
#pragma unroll
    for (int r = 0; r < 4; r++) {
      ab0[r] = acc0[r] + biasv[0];  // lo: gh_r       hi: gh_z
      ab1[r] = acc1[r] + biasv[1];  // lo: gh_n       hi: c (+cgb)
      ab2[r] = acc2[r] + biasv[2];  // lo: s (+bo_s)  hi: t (+bo_t)
    }
    float ghz_sh[4], tv_sh[4], ec_sh[4];
#pragma unroll
    for (int r = 0; r < 4; r++) {
      ghz_sh[r] = __shfl_xor(ab0[r], 8, 64);
      tv_sh[r] = __shfl_xor(ab2[r], 8, 64);
      ec_sh[r] = __shfl_xor(ecp[r], 8, 64);  // e(c(it-1)) from hi partner
    }
    const int tt = it - 1;
    if (lo) {
#pragma unroll
      for (int r = 0; r < 4; r++) {
        const int b = browbase + r;
        const float es = efun(ab2[r]);
        const size_t xoff =
            (size_t)b * (kT * kC) + (size_t)tt * kC + (M2 ? kD : 0) + d;
        const float xval = x[xoff];
        float yv, outv;
        if constexpr (M2 == 0) {
          yv = es * xval + tv_sh[r];   // y1 = e(s2v)*x1 + t2
          outv = yv * ec_sh[r];        // y1o = y1 * e(c2(t))
        } else {
          yv = es * (xval * ec_sh[r]) + tv_sh[r];  // y2 = e(s1v)*(x2*e(c1)) + t1
          outv = yv;
        }
        out[xoff] = outv;
        if constexpr (M2 == 0) y1buf[((size_t)tt * kB + b) * 512 + d] = f2b(yv);
        if (it < kT) {  // state(it) = combine(gi(it), gh(it), hprev)
          const unsigned short* gp = gi + ((size_t)it * kB + b) * kN3 + d;
          const float rr = sigm(b2f(gp[0]) + ab0[r]);
          const float zz = sigm(b2f(gp[512]) + ghz_sh[r]);
          const float nn = tanh_(b2f(gp[1024]) + rr * ab1[r]);
          const float hn = (1.f - zz) * nn + zz * hsl[r];
          hsl[r] = hn;
          hbuf[(size_t)(it & 1) * (kB * 512) + (size_t)b * 512 + d] = f2b(hn);
        }
      }
    } else {
#pragma unroll
      for (int r = 0; r < 4; r++) ecp[r] = efun(ab1[r]);  // e(c(it))
    }
    GRIDBAR(64);
  }
}

extern "C" void kernel_launch(void* const* d_in, const int* in_sizes, int n_in,
                              void* d_out, int out_size, void* d_ws, size_t ws_size,
                              hipStream_t stream) {
  (void)in_sizes; (void)n_in; (void)out_size; (void)ws_size;
  const float* x = (const float*)d_in[0];
  const float* s1_Wih = (const float*)d_in[1];
  const float* s1_Whh = (const float*)d_in[2];
  const float* s1_bih = (const float*)d_in[3];
  const float* s1_bhh = (const float*)d_in[4];
  const float* s1_Wo = (const float*)d_in[5];
  const float* s1_bo = (const float*)d_in[6];
  const float* s2_Wih = (const float*)d_in[7];
  const float* s2_Whh = (const float*)d_in[8];
  const float* s2_bih = (const float*)d_in[9];
  const float* s2_bhh = (const float*)d_in[10];
  const float* s2_Wo = (const float*)d_in[11];
  const float* s2_bo = (const float*)d_in[12];
  const float* cg1_W = (const float*)d_in[13];
  const float* cg1_b = (const float*)d_in[14];
  const float* cg2_W = (const float*)d_in[15];
  const float* cg2_b = (const float*)d_in[16];
  float* out = (float*)d_out;
  char* ws = (char*)d_ws;

  // ws layout (bytes):
  //   gi   @ 0          : T*B*1536 bf16 = 100663296 (reused for gi2 then gi1)
  //   y1   @ 100663296  : T*B*512  bf16 = 33554432
  //   hb1  @ 134217728  : 2*B*512  bf16 = 131072
  //   hb2  @ 134348800  : 131072
  //   bars @ 134479872  : 128
  unsigned short* gi = (unsigned short*)(ws);
  unsigned short* y1b = (unsigned short*)(ws + 100663296);
  unsigned short* hb1 = (unsigned short*)(ws + 134217728);
  unsigned short* hb2 = (unsigned short*)(ws + 134348800);
  int* bar1 = (int*)(ws + 134479872);
  int* bar2 = (int*)(ws + 134479936);

  hipMemsetAsync(ws + 134479872, 0, 128, stream);

  dim3 gg(24, 512);
  gemm_gi_kernel<0><<<gg, 256, 0, stream>>>(x, nullptr, s2_Wih, s2_bih, gi);
  chain_kernel<0><<<64, 256, 0, stream>>>(x, gi, s2_Whh, cg2_W, s2_Wo, s2_bhh,
                                          cg2_b, s2_bo, y1b, out, hb1, bar1,
                                          bar1 + 4);
  gemm_gi_kernel<1><<<gg, 256, 0, stream>>>(nullptr, y1b, s1_Wih, s1_bih, gi);
  chain_kernel<1><<<64, 256, 0, stream>>>(x, gi, s1_Whh, cg1_W, s1_Wo, s1_bhh,
                                          cg1_b, s1_bo, nullptr, out, hb2, bar2,
                                          bar2 + 4);
}

// Round 2
// 5856.791 us; speedup vs baseline: 2.3154x; 2.3154x over previous
//
#include <hip/hip_runtime.h>
#include <math.h>

constexpr int kT = 512;
constexpr int kC = 1024;
constexpr int kD = 512;

typedef __attribute__((ext_vector_type(8))) short bf16x8;
typedef __attribute__((ext_vector_type(4))) float f32x4;
typedef __attribute__((ext_vector_type(4))) unsigned int u32x4;
typedef __attribute__((ext_vector_type(2))) unsigned long long u64x2;

__device__ __forceinline__ float b2f(unsigned short u) {
  unsigned int v = ((unsigned int)u) << 16;
  return __builtin_bit_cast(float, v);
}
__device__ __forceinline__ unsigned short f2b(float f) {
  unsigned int u = __builtin_bit_cast(unsigned int, f);
  u += 0x7fffu + ((u >> 16) & 1u);
  return (unsigned short)(u >> 16);
}
__device__ __forceinline__ float sigm(float x) {
  x = fminf(15.f, fmaxf(-15.f, x));
  return 1.f / (1.f + __expf(-x));
}
__device__ __forceinline__ float tanh_(float x) {
  x = fminf(15.f, fmaxf(-15.f, x));
  float e2 = __expf(2.f * x);
  return (e2 - 1.f) / (e2 + 1.f);
}
__device__ __forceinline__ float efun(float s) {
  // exp(CLAMP*0.636*atan(s/CLAMP)), CLAMP=5
  return __expf((5.0f * 0.636f) * atanf(s * 0.2f));
}

// device-coherent (MALL) 16B load: two 8B relaxed agent atomic loads
__device__ __forceinline__ bf16x8 ldc16(const unsigned short* p) {
  u64x2 t;
  t.x = __hip_atomic_load((const unsigned long long*)p, __ATOMIC_RELAXED,
                          __HIP_MEMORY_SCOPE_AGENT);
  t.y = __hip_atomic_load(((const unsigned long long*)p) + 1, __ATOMIC_RELAXED,
                          __HIP_MEMORY_SCOPE_AGENT);
  return __builtin_bit_cast(bf16x8, t);
}
// device-coherent 2B store
__device__ __forceinline__ void st16c(unsigned short* p, unsigned short v) {
  __hip_atomic_store(p, v, __ATOMIC_RELAXED, __HIP_MEMORY_SCOPE_AGENT);
}
__device__ __forceinline__ void pollone(const unsigned int* p, unsigned int tgt) {
  while (__hip_atomic_load(p, __ATOMIC_RELAXED, __HIP_MEMORY_SCOPE_AGENT) < tgt)
    __builtin_amdgcn_s_sleep(1);
}

// One persistent kernel, 128 blocks x 256 threads.
// Blocks 0..63   = chain A (s2 GRU / y1 / y1o, out[:, :, :512]), superstep s -> it = s
// Blocks 64..127 = chain B (s1 GRU / y2,       out[:, :, 512:]), superstep s -> it = s-2
// Per step: P = hprev @ [Whh_r|Whh_z|Whh_n|cgW|Wo_s|Wo_t] (tiles 0-2)
//           GI = src2 @ [Wih_r|Wih_z|Wih_n|pad]            (tiles 3-4)
// where src2 = cvt_bf16(x2(it)) for A, y1(it) for B.
__global__ __launch_bounds__(256, 1) void fused_glow_kernel(
    const float* __restrict__ x,
    const float* __restrict__ A_Wih, const float* __restrict__ A_Whh,
    const float* __restrict__ A_bih, const float* __restrict__ A_bhh,
    const float* __restrict__ A_Wo, const float* __restrict__ A_bo,
    const float* __restrict__ A_cgW, const float* __restrict__ A_cgb,
    const float* __restrict__ B_Wih, const float* __restrict__ B_Whh,
    const float* __restrict__ B_bih, const float* __restrict__ B_bhh,
    const float* __restrict__ B_Wo, const float* __restrict__ B_bo,
    const float* __restrict__ B_cgW, const float* __restrict__ B_cgb,
    unsigned short* __restrict__ y1buf, float* __restrict__ out,
    unsigned short* __restrict__ hbA, unsigned short* __restrict__ hbB,
    unsigned int* __restrict__ flags) {
  const int g = blockIdx.x;
  const bool isA = (g < 64);
  const int gl = isA ? g : (g - 64);
  const int tid = threadIdx.x;
  const int w = tid >> 6;
  const int l = tid & 63;
  const int q = l & 15;
  const int kg = l >> 4;
  const bool lo = (q < 8);
  const int qm = q & 7;
  const int d = 8 * gl + qm;
  const int browbase = 16 * w + 4 * kg;

  const float* Wih = isA ? A_Wih : B_Wih;
  const float* Whh = isA ? A_Whh : B_Whh;
  const float* bih = isA ? A_bih : B_bih;
  const float* bhh = isA ? A_bhh : B_bhh;
  const float* Wo = isA ? A_Wo : B_Wo;
  const float* bo = isA ? A_bo : B_bo;
  const float* cgW = isA ? A_cgW : B_cgW;
  const float* cgb = isA ? A_cgb : B_cgb;
  unsigned short* hbuf = isA ? hbA : hbB;

  // ---- stage 72 weight rows (+8 zero rows) as bf16, XOR-swizzled 16B chunks
  __shared__ __attribute__((aligned(16))) unsigned short wlds[80 * 512];
  for (int c = tid; c < 80 * 64; c += 256) {
    const int u = c >> 6, kb = c & 63;
    const int s8 = 8 * gl + (u & 7);
    const int sel = u >> 3;
    u32x4 v = {0u, 0u, 0u, 0u};
    if (sel < 9) {
      const float* wrp = (sel == 0)   ? Whh + (size_t)s8 * kD
                         : (sel == 1) ? Whh + (size_t)(512 + s8) * kD
                         : (sel == 2) ? Whh + (size_t)(1024 + s8) * kD
                         : (sel == 3) ? cgW + (size_t)s8 * kD
                         : (sel == 4) ? Wo + (size_t)s8 * kD
                         : (sel == 5) ? Wo + (size_t)(512 + s8) * kD
                         : (sel == 6) ? Wih + (size_t)s8 * kD
                         : (sel == 7) ? Wih + (size_t)(512 + s8) * kD
                                      : Wih + (size_t)(1024 + s8) * kD;
      const float* p = wrp + kb * 8;
#pragma unroll
      for (int j = 0; j < 4; j++)
        v[j] = (unsigned int)f2b(p[2 * j]) | ((unsigned int)f2b(p[2 * j + 1]) << 16);
    }
    const int byteoff = u * 1024 + ((kb * 16) ^ ((u & 7) << 4));
    *(u32x4*)((char*)wlds + byteoff) = v;
  }

  float biasv[5];
  biasv[0] = lo ? bhh[d] : bhh[512 + d];
  biasv[1] = lo ? bhh[1024 + d] : cgb[d];
  biasv[2] = lo ? bo[d] : bo[512 + d];
  biasv[3] = lo ? bih[d] : bih[512 + d];
  biasv[4] = lo ? bih[1024 + d] : 0.f;

  float hsl[4] = {0.f, 0.f, 0.f, 0.f};
  float ecp[4];
#pragma unroll
  for (int r = 0; r < 4; r++) ecp[r] = efun(cgb[d]);

  float x1pf[4] = {0.f, 0.f, 0.f, 0.f};
  float x2pf[4] = {0.f, 0.f, 0.f, 0.f};
  f32x4 xraw[32];

  // pre-loop prefetch for A: x2(0) raw
  if (isA) {
    const float* xp = x + (size_t)(16 * w + q) * (kT * kC) + kD + kg * 8;
#pragma unroll
    for (int kk = 0; kk < 16; kk++) {
      xraw[2 * kk] = *(const f32x4*)(xp + kk * 32);
      xraw[2 * kk + 1] = *(const f32x4*)(xp + kk * 32 + 4);
    }
  }
  __syncthreads();  // LDS staging complete

  const int sw = qm << 4;
  for (int s = 0; s <= 514; ++s) {
    const int it = isA ? s : (s - 2);
    const bool act = isA ? (s <= 512) : (s >= 2);

    bf16x8 ax[16];
    if (isA) {
      if (tid < 64) pollone(flags + (size_t)tid * 32, (unsigned)s);
      __syncthreads();
      if (act) {  // convert prefetched x2(it) fp32 -> bf16 fragments
#pragma unroll
        for (int kk = 0; kk < 16; kk++) {
          bf16x8 t;
#pragma unroll
          for (int j = 0; j < 4; j++) {
            t[j] = (short)f2b(xraw[2 * kk][j]);
            t[j + 4] = (short)f2b(xraw[2 * kk + 1][j]);
          }
          ax[kk] = t;
        }
      }
    } else {
      if (tid < 64) pollone(flags + (size_t)tid * 32, (unsigned)s);  // A-flags
      __syncthreads();
      if (act) {  // y1(it) ready now; issue loads before waiting B-peers
        const int ity = it > 511 ? 511 : it;
        const unsigned short* yp =
            y1buf + ((size_t)ity * 64 + 16 * w + q) * 512 + kg * 8;
#pragma unroll
        for (int kk = 0; kk < 16; kk++) ax[kk] = ldc16(yp + kk * 32);
      }
      if (tid < 64) pollone(flags + (size_t)(64 + tid) * 32, (unsigned)s);
      __syncthreads();
    }

    if (act) {
      const unsigned short* hp = hbuf + (size_t)((it + 1) & 1) * 32768 +
                                 (size_t)(16 * w + q) * 512 + kg * 8;
      bf16x8 ah[16];
#pragma unroll
      for (int kk = 0; kk < 16; kk++) ah[kk] = ldc16(hp + kk * 32);

      f32x4 acc0 = {0.f, 0.f, 0.f, 0.f}, acc1 = {0.f, 0.f, 0.f, 0.f};
      f32x4 acc2 = {0.f, 0.f, 0.f, 0.f}, acc3 = {0.f, 0.f, 0.f, 0.f};
      f32x4 acc4 = {0.f, 0.f, 0.f, 0.f};
#pragma unroll
      for (int kk = 0; kk < 16; kk++) {
        const int kbyte = (kk * 32 + kg * 8) * 2;
        bf16x8 b0 = *(const bf16x8*)((const char*)wlds + q * 1024 + (kbyte ^ sw));
        bf16x8 b1 =
            *(const bf16x8*)((const char*)wlds + (16 + q) * 1024 + (kbyte ^ sw));
        bf16x8 b2 =
            *(const bf16x8*)((const char*)wlds + (32 + q) * 1024 + (kbyte ^ sw));
        bf16x8 b3 =
            *(const bf16x8*)((const char*)wlds + (48 + q) * 1024 + (kbyte ^ sw));
        bf16x8 b4 =
            *(const bf16x8*)((const char*)wlds + (64 + q) * 1024 + (kbyte ^ sw));
        acc0 = __builtin_amdgcn_mfma_f32_16x16x32_bf16(ah[kk], b0, acc0, 0, 0, 0);
        acc1 = __builtin_amdgcn_mfma_f32_16x16x32_bf16(ah[kk], b1, acc1, 0, 0, 0);
        acc2 = __builtin_amdgcn_mfma_f32_16x16x32_bf16(ah[kk], b2, acc2, 0, 0, 0);
        acc3 = __builtin_amdgcn_mfma_f32_16x16x32_bf16(ax[kk], b3, acc3, 0, 0, 0);
        acc4 = __builtin_amdgcn_mfma_f32_16x16x32_bf16(ax[kk], b4, acc4, 0, 0, 0);
      }
      float ab0[4], ab1[4], ab2[4], ab3[4], ab4[4];
#pragma unroll
      for (int r = 0; r < 4; r++) {
        ab0[r] = acc0[r] + biasv[0];  // lo: gh_r   hi: gh_z
        ab1[r] = acc1[r] + biasv[1];  // lo: gh_n   hi: c
        ab2[r] = acc2[r] + biasv[2];  // lo: s      hi: t
        ab3[r] = acc3[r] + biasv[3];  // lo: gi_r   hi: gi_z
        ab4[r] = acc4[r] + biasv[4];  // lo: gi_n   hi: unused
      }
      float ghz[4], tv[4], giz[4], ec_sh[4];
#pragma unroll
      for (int r = 0; r < 4; r++) {
        ghz[r] = __shfl_xor(ab0[r], 8, 64);
        tv[r] = __shfl_xor(ab2[r], 8, 64);
        giz[r] = __shfl_xor(ab3[r], 8, 64);
        ec_sh[r] = __shfl_xor(ecp[r], 8, 64);  // e(c(it-1.. prev step))
      }
      const int tt = it - 1;
      if (lo) {
#pragma unroll
        for (int r = 0; r < 4; r++) {
          const int b = browbase + r;
          if (it >= 1) {
            const float es = efun(ab2[r]);
            const size_t ooff =
                (size_t)b * (kT * kC) + (size_t)tt * kC + (isA ? 0 : kD) + d;
            if (isA) {
              const float yv = es * x1pf[r] + tv[r];  // y1 = e(s2v)*x1 + t2
              out[ooff] = yv * ec_sh[r];              // y1o = y1 * e(c2)
              st16c(y1buf + ((size_t)tt * 64 + b) * 512 + d, f2b(yv));
            } else {
              out[ooff] = es * (x2pf[r] * ec_sh[r]) + tv[r];  // y2
            }
          }
          if (it <= 511) {
            const float rr = sigm(ab3[r] + ab0[r]);
            const float zz = sigm(giz[r] + ghz[r]);
            const float nn = tanh_(ab4[r] + rr * ab1[r]);
            const float hn = (1.f - zz) * nn + zz * hsl[r];
            hsl[r] = hn;
            st16c(hbuf + (size_t)(it & 1) * 32768 + (size_t)b * 512 + d, f2b(hn));
          }
        }
      } else {
#pragma unroll
        for (int r = 0; r < 4; r++) ecp[r] = efun(ab1[r]);  // e(c(it))
      }
    }

    // ---- arrival: drain data stores, then flag
    asm volatile("s_waitcnt vmcnt(0)" ::: "memory");
    __syncthreads();
    if (tid == 0)
      __hip_atomic_store(flags + (size_t)g * 32, (unsigned)(s + 1),
                         __ATOMIC_RELAXED, __HIP_MEMORY_SCOPE_AGENT);

    // ---- prefetch for superstep s+1 (plain cached loads)
    if (isA) {
      const int itn = (s + 1 < 511) ? (s + 1) : 511;
      const float* xp =
          x + (size_t)(16 * w + q) * (kT * kC) + (size_t)itn * kC + kD + kg * 8;
#pragma unroll
      for (int kk = 0; kk < 16; kk++) {
        xraw[2 * kk] = *(const f32x4*)(xp + kk * 32);
        xraw[2 * kk + 1] = *(const f32x4*)(xp + kk * 32 + 4);
      }
      if (lo) {
        const int ttn = (s < 511) ? s : 511;
#pragma unroll
        for (int r = 0; r < 4; r++)
          x1pf[r] = x[(size_t)(browbase + r) * (kT * kC) + (size_t)ttn * kC + d];
      }
    } else {
      if (lo) {
        const int ttn2 = s - 2 < 0 ? 0 : (s - 2 > 511 ? 511 : s - 2);
#pragma unroll
        for (int r = 0; r < 4; r++)
          x2pf[r] =
              x[(size_t)(browbase + r) * (kT * kC) + (size_t)ttn2 * kC + kD + d];
      }
    }
  }
}

extern "C" void kernel_launch(void* const* d_in, const int* in_sizes, int n_in,
                              void* d_out, int out_size, void* d_ws, size_t ws_size,
                              hipStream_t stream) {
  (void)in_sizes; (void)n_in; (void)out_size; (void)ws_size;
  const float* x = (const float*)d_in[0];
  const float* s1_Wih = (const float*)d_in[1];
  const float* s1_Whh = (const float*)d_in[2];
  const float* s1_bih = (const float*)d_in[3];
  const float* s1_bhh = (const float*)d_in[4];
  const float* s1_Wo = (const float*)d_in[5];
  const float* s1_bo = (const float*)d_in[6];
  const float* s2_Wih = (const float*)d_in[7];
  const float* s2_Whh = (const float*)d_in[8];
  const float* s2_bih = (const float*)d_in[9];
  const float* s2_bhh = (const float*)d_in[10];
  const float* s2_Wo = (const float*)d_in[11];
  const float* s2_bo = (const float*)d_in[12];
  const float* cg1_W = (const float*)d_in[13];
  const float* cg1_b = (const float*)d_in[14];
  const float* cg2_W = (const float*)d_in[15];
  const float* cg2_b = (const float*)d_in[16];
  float* out = (float*)d_out;
  char* ws = (char*)d_ws;

  // ws layout (bytes):
  //   y1buf @ 0        : T*B*512 bf16 = 33,554,432
  //   hbA   @ 33554432 : 2*64*512 bf16 = 131,072
  //   hbB   @ 33685504 : 131,072
  //   flags @ 33816576 : 128 * 128B = 16,384
  unsigned short* y1b = (unsigned short*)ws;
  unsigned short* hbA = (unsigned short*)(ws + 33554432);
  unsigned short* hbB = (unsigned short*)(ws + 33685504);
  unsigned int* flags = (unsigned int*)(ws + 33816576);

  hipMemsetAsync(ws + 33554432, 0, 131072 * 2 + 16384, stream);

  fused_glow_kernel<<<128, 256, 0, stream>>>(
      x,
      // chain A = s2 + cg2
      s2_Wih, s2_Whh, s2_bih, s2_bhh, s2_Wo, s2_bo, cg2_W, cg2_b,
      // chain B = s1 + cg1
      s1_Wih, s1_Whh, s1_bih, s1_bhh, s1_Wo, s1_bo, cg1_W, cg1_b,
      y1b, out, hbA, hbB, flags);
}

// Round 3
// 4067.360 us; speedup vs baseline: 3.3340x; 1.4399x over previous
//
#include <hip/hip_runtime.h>
#include <math.h>

constexpr int kT = 512;
constexpr int kC = 1024;
constexpr int kD = 512;

typedef __attribute__((ext_vector_type(8))) short bf16x8;
typedef __attribute__((ext_vector_type(4))) float f32x4;
typedef __attribute__((ext_vector_type(4))) unsigned int u32x4;

__device__ __forceinline__ float b2f(unsigned short u) {
  unsigned int v = ((unsigned int)u) << 16;
  return __builtin_bit_cast(float, v);
}
__device__ __forceinline__ unsigned short f2b(float f) {
  unsigned int u = __builtin_bit_cast(unsigned int, f);
  u += 0x7fffu + ((u >> 16) & 1u);
  return (unsigned short)(u >> 16);
}
__device__ __forceinline__ float sigm(float x) {
  x = fminf(15.f, fmaxf(-15.f, x));
  return 1.f / (1.f + __expf(-x));
}
__device__ __forceinline__ float tanh_(float x) {
  x = fminf(15.f, fmaxf(-15.f, x));
  float e2 = __expf(2.f * x);
  return (e2 - 1.f) / (e2 + 1.f);
}
__device__ __forceinline__ float efun(float s) {
  // exp(CLAMP*0.636*atan(s/CLAMP)), CLAMP=5
  return __expf((5.0f * 0.636f) * atanf(s * 0.2f));
}

// write-through-to-MALL 2B store (non-atomic -> coalesces across lanes)
__device__ __forceinline__ void st_b16_wt(unsigned short* p, unsigned short v) {
  asm volatile("global_store_short %0, %1, off sc0 sc1" ::"v"(p),
               "v"((unsigned int)v)
               : "memory");
}

__device__ __forceinline__ void poll_ge(const unsigned int* p, unsigned int tgt) {
  while (__hip_atomic_load(p, __ATOMIC_RELAXED, __HIP_MEMORY_SCOPE_AGENT) < tgt)
    __builtin_amdgcn_s_sleep(1);
}
__device__ __forceinline__ void poll2_ge(const unsigned int* pa,
                                         const unsigned int* pb,
                                         unsigned int tgt) {
  for (;;) {
    unsigned int a =
        __hip_atomic_load(pa, __ATOMIC_RELAXED, __HIP_MEMORY_SCOPE_AGENT);
    unsigned int b =
        __hip_atomic_load(pb, __ATOMIC_RELAXED, __HIP_MEMORY_SCOPE_AGENT);
    if (a >= tgt && b >= tgt) return;
    __builtin_amdgcn_s_sleep(1);
  }
}

// x[:, :, D:] fp32 -> xb2[t][b][512] bf16
__global__ __launch_bounds__(256) void cvt_x2_kernel(
    const float* __restrict__ x, unsigned short* __restrict__ xb2) {
  const int idx = blockIdx.x * 256 + threadIdx.x;  // one per 8 elems
  const int e = idx * 8;
  const int dd = e & 511;
  const int tb = e >> 9;
  const int b = tb & 63;
  const int t = tb >> 6;
  const float* src = x + ((size_t)b * kT + t) * kC + kD + dd;
  f32x4 v0 = *(const f32x4*)src;
  f32x4 v1 = *(const f32x4*)(src + 4);
  bf16x8 o;
#pragma unroll
  for (int j = 0; j < 4; j++) {
    o[j] = (short)f2b(v0[j]);
    o[j + 4] = (short)f2b(v1[j]);
  }
  *(bf16x8*)(xb2 + e) = o;
}

// One persistent kernel, 128 blocks x 256 threads.
// Blocks 0..63   = chain A (s2 GRU / y1 / y1o, out[:, :, :512]), superstep s = it
// Blocks 64..127 = chain B (s1 GRU / y2,       out[:, :, 512:]), superstep s, it = s-2
// Exchange protocol: per-timestep fresh buffers; producer stores sc0sc1
// (write-through MALL), vmcnt(0) drain, one agent atomicAdd per block on
// arr[chain][s]; consumer polls that single counter ==64, then plain cached
// loads (cold L2 miss -> MALL -> L2-shared within the XCD).
__global__ __launch_bounds__(256, 1) void fused_glow_kernel(
    const float* __restrict__ x, const unsigned short* __restrict__ xb2,
    const float* __restrict__ A_Wih, const float* __restrict__ A_Whh,
    const float* __restrict__ A_bih, const float* __restrict__ A_bhh,
    const float* __restrict__ A_Wo, const float* __restrict__ A_bo,
    const float* __restrict__ A_cgW, const float* __restrict__ A_cgb,
    const float* __restrict__ B_Wih, const float* __restrict__ B_Whh,
    const float* __restrict__ B_bih, const float* __restrict__ B_bhh,
    const float* __restrict__ B_Wo, const float* __restrict__ B_bo,
    const float* __restrict__ B_cgW, const float* __restrict__ B_cgb,
    unsigned short* __restrict__ y1buf, float* __restrict__ out,
    unsigned short* __restrict__ hbA, unsigned short* __restrict__ hbB,
    unsigned int* __restrict__ arrA, unsigned int* __restrict__ arrB) {
  const int g = blockIdx.x;
  const bool isA = (g < 64);
  const int gl = isA ? g : (g - 64);
  const int tid = threadIdx.x;
  const int w = tid >> 6;
  const int l = tid & 63;
  const int q = l & 15;
  const int kg = l >> 4;
  const bool lo = (q < 8);
  const int qm = q & 7;
  const int d = 8 * gl + qm;
  const int browbase = 16 * w + 4 * kg;
  const int arow = 16 * w + q;
  const int acol = kg * 8;

  const float* Wih = isA ? A_Wih : B_Wih;
  const float* Whh = isA ? A_Whh : B_Whh;
  const float* bih = isA ? A_bih : B_bih;
  const float* bhh = isA ? A_bhh : B_bhh;
  const float* Wo = isA ? A_Wo : B_Wo;
  const float* bo = isA ? A_bo : B_bo;
  const float* cgW = isA ? A_cgW : B_cgW;
  const float* cgb = isA ? A_cgb : B_cgb;
  unsigned short* hbuf = isA ? hbA : hbB;

  // ---- stage 72 weight rows (+8 zero rows) as bf16, XOR-swizzled 16B chunks
  __shared__ __attribute__((aligned(16))) unsigned short wlds[80 * 512];
  for (int c = tid; c < 80 * 64; c += 256) {
    const int u = c >> 6, kb = c & 63;
    const int s8 = 8 * gl + (u & 7);
    const int sel = u >> 3;
    u32x4 v = {0u, 0u, 0u, 0u};
    if (sel < 9) {
      const float* wrp = (sel == 0)   ? Whh + (size_t)s8 * kD
                         : (sel == 1) ? Whh + (size_t)(512 + s8) * kD
                         : (sel == 2) ? Whh + (size_t)(1024 + s8) * kD
                         : (sel == 3) ? cgW + (size_t)s8 * kD
                         : (sel == 4) ? Wo + (size_t)s8 * kD
                         : (sel == 5) ? Wo + (size_t)(512 + s8) * kD
                         : (sel == 6) ? Wih + (size_t)s8 * kD
                         : (sel == 7) ? Wih + (size_t)(512 + s8) * kD
                                      : Wih + (size_t)(1024 + s8) * kD;
      const float* p = wrp + kb * 8;
#pragma unroll
      for (int j = 0; j < 4; j++)
        v[j] = (unsigned int)f2b(p[2 * j]) | ((unsigned int)f2b(p[2 * j + 1]) << 16);
    }
    const int byteoff = u * 1024 + ((kb * 16) ^ ((u & 7) << 4));
    *(u32x4*)((char*)wlds + byteoff) = v;
  }

  float biasv[5];
  biasv[0] = lo ? bhh[d] : bhh[512 + d];
  biasv[1] = lo ? bhh[1024 + d] : cgb[d];
  biasv[2] = lo ? bo[d] : bo[512 + d];
  biasv[3] = lo ? bih[d] : bih[512 + d];
  biasv[4] = lo ? bih[1024 + d] : 0.f;

  float hsl[4] = {0.f, 0.f, 0.f, 0.f};
  float ecp[4];
#pragma unroll
  for (int r = 0; r < 4; r++) ecp[r] = efun(cgb[d]);

  __syncthreads();  // LDS staging complete

  const int sw = qm << 4;
  const int s0 = isA ? 0 : 2;
  const int s1 = isA ? 512 : 514;
#pragma unroll 1
  for (int s = s0; s <= s1; ++s) {
    const int it = isA ? s : (s - 2);

    bf16x8 ax[16];
    float xopf[4] = {0.f, 0.f, 0.f, 0.f};
    if (isA) {
      // x-side loads are input-only: issue BEFORE the poll to hide latency
      const int itc = it < 511 ? it : 511;
      const unsigned short* xp = xb2 + ((size_t)itc * 64 + arow) * 512 + acol;
#pragma unroll
      for (int kk = 0; kk < 16; kk++) ax[kk] = *(const bf16x8*)(xp + kk * 32);
      if (lo) {
        const int ttc = s >= 1 ? s - 1 : 0;
#pragma unroll
        for (int r = 0; r < 4; r++)
          xopf[r] = x[(size_t)(browbase + r) * (kT * kC) + (size_t)ttc * kC + d];
      }
      if (s >= 1) {
        if (tid == 0) poll_ge(arrA + (s - 1), 64u);
        __syncthreads();
      }
    } else {
      if (lo) {
        const int ttc = it >= 1 ? it - 1 : 0;
#pragma unroll
        for (int r = 0; r < 4; r++)
          xopf[r] =
              x[(size_t)(browbase + r) * (kT * kC) + (size_t)ttc * kC + kD + d];
      }
      if (tid == 0) {
        const unsigned int* pa = arrA + (s - 1 < 512 ? s - 1 : 512);
        if (s >= 3)
          poll2_ge(pa, arrB + (s - 1), 64u);
        else
          poll_ge(pa, 64u);
      }
      __syncthreads();
      const int ity = it < 511 ? it : 511;
      const unsigned short* yp = y1buf + ((size_t)ity * 64 + arow) * 512 + acol;
#pragma unroll
      for (int kk = 0; kk < 16; kk++) ax[kk] = *(const bf16x8*)(yp + kk * 32);
    }

    // h(prev): slot s (A) / it (B); slot 0 is zeroed
    const unsigned short* hp =
        hbuf + (size_t)(isA ? s : it) * 32768 + (size_t)arow * 512 + acol;
    bf16x8 ah[16];
#pragma unroll
    for (int kk = 0; kk < 16; kk++) ah[kk] = *(const bf16x8*)(hp + kk * 32);

    f32x4 acc0 = {0.f, 0.f, 0.f, 0.f}, acc1 = {0.f, 0.f, 0.f, 0.f};
    f32x4 acc2 = {0.f, 0.f, 0.f, 0.f}, acc3 = {0.f, 0.f, 0.f, 0.f};
    f32x4 acc4 = {0.f, 0.f, 0.f, 0.f};
#pragma unroll
    for (int kk = 0; kk < 16; kk++) {
      const int kbyte = (kk * 32 + kg * 8) * 2;
      bf16x8 b0 = *(const bf16x8*)((const char*)wlds + q * 1024 + (kbyte ^ sw));
      bf16x8 b1 =
          *(const bf16x8*)((const char*)wlds + (16 + q) * 1024 + (kbyte ^ sw));
      bf16x8 b2 =
          *(const bf16x8*)((const char*)wlds + (32 + q) * 1024 + (kbyte ^ sw));
      bf16x8 b3 =
          *(const bf16x8*)((const char*)wlds + (48 + q) * 1024 + (kbyte ^ sw));
      bf16x8 b4 =
          *(const bf16x8*)((const char*)wlds + (64 + q) * 1024 + (kbyte ^ sw));
      acc0 = __builtin_amdgcn_mfma_f32_16x16x32_bf16(ah[kk], b0, acc0, 0, 0, 0);
      acc1 = __builtin_amdgcn_mfma_f32_16x16x32_bf16(ah[kk], b1, acc1, 0, 0, 0);
      acc2 = __builtin_amdgcn_mfma_f32_16x16x32_bf16(ah[kk], b2, acc2, 0, 0, 0);
      acc3 = __builtin_amdgcn_mfma_f32_16x16x32_bf16(ax[kk], b3, acc3, 0, 0, 0);
      acc4 = __builtin_amdgcn_mfma_f32_16x16x32_bf16(ax[kk], b4, acc4, 0, 0, 0);
    }
    float ab0[4], ab1[4], ab2[4], ab3[4], ab4[4];
#pragma unroll
    for (int r = 0; r < 4; r++) {
      ab0[r] = acc0[r] + biasv[0];  // lo: gh_r   hi: gh_z
      ab1[r] = acc1[r] + biasv[1];  // lo: gh_n   hi: c
      ab2[r] = acc2[r] + biasv[2];  // lo: s      hi: t
      ab3[r] = acc3[r] + biasv[3];  // lo: gi_r   hi: gi_z
      ab4[r] = acc4[r] + biasv[4];  // lo: gi_n   hi: unused
    }
    float ghz[4], tv[4], giz[4], ec_sh[4];
#pragma unroll
    for (int r = 0; r < 4; r++) {
      ghz[r] = __shfl_xor(ab0[r], 8, 64);
      tv[r] = __shfl_xor(ab2[r], 8, 64);
      giz[r] = __shfl_xor(ab3[r], 8, 64);
      ec_sh[r] = __shfl_xor(ecp[r], 8, 64);  // e(c) from previous superstep
    }
    const int tt = it - 1;
    if (lo) {
#pragma unroll
      for (int r = 0; r < 4; r++) {
        const int b = browbase + r;
        if (it >= 1) {
          const float es = efun(ab2[r]);
          const size_t ooff =
              (size_t)b * (kT * kC) + (size_t)tt * kC + (isA ? 0 : kD) + d;
          if (isA) {
            const float yv = es * xopf[r] + tv[r];  // y1 = e(s2v)*x1 + t2
            out[ooff] = yv * ec_sh[r];              // y1o = y1 * e(c2)
            st_b16_wt(y1buf + ((size_t)tt * 64 + b) * 512 + d, f2b(yv));
          } else {
            out[ooff] = es * (xopf[r] * ec_sh[r]) + tv[r];  // y2
          }
        }
        if (it <= 511) {
          const float rr = sigm(ab3[r] + ab0[r]);
          const float zz = sigm(giz[r] + ghz[r]);
          const float nn = tanh_(ab4[r] + rr * ab1[r]);
          const float hn = (1.f - zz) * nn + zz * hsl[r];
          hsl[r] = hn;
          st_b16_wt(hbuf + (size_t)(it + 1) * 32768 + (size_t)b * 512 + d,
                    f2b(hn));
        }
      }
    } else {
#pragma unroll
      for (int r = 0; r < 4; r++) ecp[r] = efun(ab1[r]);  // e(c(it))
    }

    // ---- arrival: drain write-through stores, then one MALL atomic add
    asm volatile("s_waitcnt vmcnt(0)" ::: "memory");
    __syncthreads();
    if (tid == 0)
      __hip_atomic_fetch_add((isA ? arrA : arrB) + s, 1u, __ATOMIC_RELAXED,
                             __HIP_MEMORY_SCOPE_AGENT);
  }
}

extern "C" void kernel_launch(void* const* d_in, const int* in_sizes, int n_in,
                              void* d_out, int out_size, void* d_ws, size_t ws_size,
                              hipStream_t stream) {
  (void)in_sizes; (void)n_in; (void)out_size; (void)ws_size;
  const float* x = (const float*)d_in[0];
  const float* s1_Wih = (const float*)d_in[1];
  const float* s1_Whh = (const float*)d_in[2];
  const float* s1_bih = (const float*)d_in[3];
  const float* s1_bhh = (const float*)d_in[4];
  const float* s1_Wo = (const float*)d_in[5];
  const float* s1_bo = (const float*)d_in[6];
  const float* s2_Wih = (const float*)d_in[7];
  const float* s2_Whh = (const float*)d_in[8];
  const float* s2_bih = (const float*)d_in[9];
  const float* s2_bhh = (const float*)d_in[10];
  const float* s2_Wo = (const float*)d_in[11];
  const float* s2_bo = (const float*)d_in[12];
  const float* cg1_W = (const float*)d_in[13];
  const float* cg1_b = (const float*)d_in[14];
  const float* cg2_W = (const float*)d_in[15];
  const float* cg2_b = (const float*)d_in[16];
  float* out = (float*)d_out;
  char* ws = (char*)d_ws;

  // ws layout (bytes):
  //   xb2  @ 0          : T*B*512 bf16   = 33,554,432
  //   y1   @ 33554432   : T*B*512 bf16   = 33,554,432
  //   hbA  @ 67108864   : 513*B*512 bf16 = 33,619,968
  //   hbB  @ 100728832  : 33,619,968
  //   arr  @ 134348800  : arrA[520], arrB[520] u32 (8 KB region)
  unsigned short* xb2 = (unsigned short*)ws;
  unsigned short* y1b = (unsigned short*)(ws + 33554432);
  unsigned short* hbA = (unsigned short*)(ws + 67108864);
  unsigned short* hbB = (unsigned short*)(ws + 100728832);
  unsigned int* arrA = (unsigned int*)(ws + 134348800);
  unsigned int* arrB = arrA + 640;

  // zero: h slot 0 for both chains + arrival counters
  hipMemsetAsync(ws + 67108864, 0, 65536, stream);
  hipMemsetAsync(ws + 100728832, 0, 65536, stream);
  hipMemsetAsync(ws + 134348800, 0, 8192, stream);

  cvt_x2_kernel<<<8192, 256, 0, stream>>>(x, xb2);

  fused_glow_kernel<<<128, 256, 0, stream>>>(
      x, xb2,
      // chain A = s2 + cg2
      s2_Wih, s2_Whh, s2_bih, s2_bhh, s2_Wo, s2_bo, cg2_W, cg2_b,
      // chain B = s1 + cg1
      s1_Wih, s1_Whh, s1_bih, s1_bhh, s1_Wo, s1_bo, cg1_W, cg1_b,
      y1b, out, hbA, hbB, arrA, arrB);
}

// Round 4
// 3697.617 us; speedup vs baseline: 3.6674x; 1.1000x over previous
//
#include <hip/hip_runtime.h>
#include <math.h>

constexpr int kT = 512;
constexpr int kC = 1024;
constexpr int kD = 512;

typedef __attribute__((ext_vector_type(8))) short bf16x8;
typedef __attribute__((ext_vector_type(4))) float f32x4;
typedef __attribute__((ext_vector_type(4))) unsigned int u32x4;

__device__ __forceinline__ float b2f(unsigned short u) {
  unsigned int v = ((unsigned int)u) << 16;
  return __builtin_bit_cast(float, v);
}
__device__ __forceinline__ unsigned short f2b(float f) {
  unsigned int u = __builtin_bit_cast(unsigned int, f);
  u += 0x7fffu + ((u >> 16) & 1u);
  return (unsigned short)(u >> 16);
}
__device__ __forceinline__ float sigm(float x) {
  x = fminf(15.f, fmaxf(-15.f, x));
  return 1.f / (1.f + __expf(-x));
}
__device__ __forceinline__ float tanh_(float x) {
  x = fminf(15.f, fmaxf(-15.f, x));
  float e2 = __expf(2.f * x);
  return (e2 - 1.f) / (e2 + 1.f);
}
__device__ __forceinline__ float efun(float s) {
  // exp(CLAMP*0.636*atan(s/CLAMP)), CLAMP=5
  return __expf((5.0f * 0.636f) * atanf(s * 0.2f));
}

// write-through-to-MALL stores (non-atomic -> coalesce; no L2 allocate/RFO)
__device__ __forceinline__ void st_b16_wt(unsigned short* p, unsigned short v) {
  asm volatile("global_store_short %0, %1, off sc0 sc1" ::"v"(p),
               "v"((unsigned int)v)
               : "memory");
}
__device__ __forceinline__ void st_f32_wt(float* p, float v) {
  asm volatile("global_store_dword %0, %1, off sc0 sc1" ::"v"(p), "v"(v)
               : "memory");
}

__device__ __forceinline__ unsigned int ldflag(const unsigned int* p) {
  return __hip_atomic_load(p, __ATOMIC_RELAXED, __HIP_MEMORY_SCOPE_AGENT);
}

// x[:, :, D:] fp32 -> xb2[t][b][512] bf16
__global__ __launch_bounds__(256) void cvt_x2_kernel(
    const float* __restrict__ x, unsigned short* __restrict__ xb2) {
  const int idx = blockIdx.x * 256 + threadIdx.x;  // one per 8 elems
  const int e = idx * 8;
  const int dd = e & 511;
  const int tb = e >> 9;
  const int b = tb & 63;
  const int t = tb >> 6;
  const float* src = x + ((size_t)b * kT + t) * kC + kD + dd;
  f32x4 v0 = *(const f32x4*)src;
  f32x4 v1 = *(const f32x4*)(src + 4);
  bf16x8 o;
#pragma unroll
  for (int j = 0; j < 4; j++) {
    o[j] = (short)f2b(v0[j]);
    o[j + 4] = (short)f2b(v1[j]);
  }
  *(bf16x8*)(xb2 + e) = o;
}

// One persistent kernel, 128 blocks x 256 threads.
// Blocks 0..63   = chain A (s2 GRU / y1 / y1o, out[:, :, :512]), superstep s = it
// Blocks 64..127 = chain B (s1 GRU / y2,       out[:, :, 512:]), superstep s, it = s-2
// Exchange: per-timestep fresh buffers; producer stores sc0sc1 (write-through
// MALL), vmcnt(0) drain, then ONE relaxed agent store of (s+1) to its own
// 128B-strided flag; consumer wave 0 polls all 64 flags in parallel (__all).
__global__ __launch_bounds__(256, 1) void fused_glow_kernel(
    const float* __restrict__ x, const unsigned short* __restrict__ xb2,
    const float* __restrict__ A_Wih, const float* __restrict__ A_Whh,
    const float* __restrict__ A_bih, const float* __restrict__ A_bhh,
    const float* __restrict__ A_Wo, const float* __restrict__ A_bo,
    const float* __restrict__ A_cgW, const float* __restrict__ A_cgb,
    const float* __restrict__ B_Wih, const float* __restrict__ B_Whh,
    const float* __restrict__ B_bih, const float* __restrict__ B_bhh,
    const float* __restrict__ B_Wo, const float* __restrict__ B_bo,
    const float* __restrict__ B_cgW, const float* __restrict__ B_cgb,
    unsigned short* __restrict__ y1buf, float* __restrict__ out,
    unsigned short* __restrict__ hbA, unsigned short* __restrict__ hbB,
    unsigned int* __restrict__ flagsA, unsigned int* __restrict__ flagsB) {
  const int g = blockIdx.x;
  const bool isA = (g < 64);
  const int gl = isA ? g : (g - 64);
  const int tid = threadIdx.x;
  const int w = tid >> 6;
  const int l = tid & 63;
  const int q = l & 15;
  const int kg = l >> 4;
  const bool lo = (q < 8);
  const int qm = q & 7;
  const int d = 8 * gl + qm;
  const int browbase = 16 * w + 4 * kg;
  const int arow = 16 * w + q;
  const int acol = kg * 8;

  const float* Wih = isA ? A_Wih : B_Wih;
  const float* Whh = isA ? A_Whh : B_Whh;
  const float* bih = isA ? A_bih : B_bih;
  const float* bhh = isA ? A_bhh : B_bhh;
  const float* Wo = isA ? A_Wo : B_Wo;
  const float* bo = isA ? A_bo : B_bo;
  const float* cgW = isA ? A_cgW : B_cgW;
  const float* cgb = isA ? A_cgb : B_cgb;
  unsigned short* hbuf = isA ? hbA : hbB;
  unsigned int* myflag = (isA ? flagsA : flagsB) + (size_t)gl * 32;

  // ---- stage 72 weight rows (+8 zero rows) as bf16, 4-bit-XOR-swizzled 16B
  __shared__ __attribute__((aligned(16))) unsigned short wlds[80 * 512];
  for (int c = tid; c < 80 * 64; c += 256) {
    const int u = c >> 6, kb = c & 63;
    const int s8 = 8 * gl + (u & 7);
    const int sel = u >> 3;
    u32x4 v = {0u, 0u, 0u, 0u};
    if (sel < 9) {
      const float* wrp = (sel == 0)   ? Whh + (size_t)s8 * kD
                         : (sel == 1) ? Whh + (size_t)(512 + s8) * kD
                         : (sel == 2) ? Whh + (size_t)(1024 + s8) * kD
                         : (sel == 3) ? cgW + (size_t)s8 * kD
                         : (sel == 4) ? Wo + (size_t)s8 * kD
                         : (sel == 5) ? Wo + (size_t)(512 + s8) * kD
                         : (sel == 6) ? Wih + (size_t)s8 * kD
                         : (sel == 7) ? Wih + (size_t)(512 + s8) * kD
                                      : Wih + (size_t)(1024 + s8) * kD;
      const float* p = wrp + kb * 8;
#pragma unroll
      for (int j = 0; j < 4; j++)
        v[j] = (unsigned int)f2b(p[2 * j]) | ((unsigned int)f2b(p[2 * j + 1]) << 16);
    }
    const int byteoff = u * 1024 + ((kb * 16) ^ ((u & 15) << 4));
    *(u32x4*)((char*)wlds + byteoff) = v;
  }

  float biasv[5];
  biasv[0] = lo ? bhh[d] : bhh[512 + d];
  biasv[1] = lo ? bhh[1024 + d] : cgb[d];
  biasv[2] = lo ? bo[d] : bo[512 + d];
  biasv[3] = lo ? bih[d] : bih[512 + d];
  biasv[4] = lo ? bih[1024 + d] : 0.f;

  float hsl[4] = {0.f, 0.f, 0.f, 0.f};
  float ecp[4];
#pragma unroll
  for (int r = 0; r < 4; r++) ecp[r] = efun(cgb[d]);

  __syncthreads();  // LDS staging complete

  const int sw = q << 4;
  const int s0 = isA ? 0 : 2;
  const int s1 = isA ? 512 : 514;
#pragma unroll 1
  for (int s = s0; s <= s1; ++s) {
    const int it = isA ? s : (s - 2);

    bf16x8 ax[16];
    float xopf[4] = {0.f, 0.f, 0.f, 0.f};
    if (isA) {
      // x-side loads are input-only: issue BEFORE the poll to hide latency
      const int itc = it < 511 ? it : 511;
      const unsigned short* xp = xb2 + ((size_t)itc * 64 + arow) * 512 + acol;
#pragma unroll
      for (int kk = 0; kk < 16; kk++) ax[kk] = *(const bf16x8*)(xp + kk * 32);
      if (lo) {
        const int ttc = s >= 1 ? s - 1 : 0;
#pragma unroll
        for (int r = 0; r < 4; r++)
          xopf[r] = x[(size_t)(browbase + r) * (kT * kC) + (size_t)ttc * kC + d];
      }
      if (s >= 1) {
        if (w == 0) {
          const unsigned int* fp = flagsA + (size_t)l * 32;
          unsigned int v = ldflag(fp);
          while (!__all((int)(v >= (unsigned)s))) {
            __builtin_amdgcn_s_sleep(1);
            v = ldflag(fp);
          }
        }
        __syncthreads();
      }
    } else {
      if (lo) {
        const int ttc = it >= 1 ? it - 1 : 0;
#pragma unroll
        for (int r = 0; r < 4; r++)
          xopf[r] =
              x[(size_t)(browbase + r) * (kT * kC) + (size_t)ttc * kC + kD + d];
      }
      // phase 1: wait for A's y1(it) (usually already satisfied; A runs ahead)
      const unsigned int tgtA = (unsigned)(s <= 513 ? s : 513);
      if (w == 0) {
        const unsigned int* fp = flagsA + (size_t)l * 32;
        unsigned int v = ldflag(fp);
        while (!__all((int)(v >= tgtA))) {
          __builtin_amdgcn_s_sleep(1);
          v = ldflag(fp);
        }
      }
      __syncthreads();
      // issue y1 loads before waiting on B peers
      const int ity = it < 511 ? it : 511;
      const unsigned short* yp = y1buf + ((size_t)ity * 64 + arow) * 512 + acol;
#pragma unroll
      for (int kk = 0; kk < 16; kk++) ax[kk] = *(const bf16x8*)(yp + kk * 32);
      if (s >= 3) {
        if (w == 0) {
          const unsigned int* fp = flagsB + (size_t)l * 32;
          unsigned int v = ldflag(fp);
          while (!__all((int)(v >= (unsigned)s))) {
            __builtin_amdgcn_s_sleep(1);
            v = ldflag(fp);
          }
        }
        __syncthreads();
      }
    }

    // h(prev): slot s (A) / it (B); slot 0 is zeroed
    const unsigned short* hp =
        hbuf + (size_t)(isA ? s : it) * 32768 + (size_t)arow * 512 + acol;
    bf16x8 ah[16];
#pragma unroll
    for (int kk = 0; kk < 16; kk++) ah[kk] = *(const bf16x8*)(hp + kk * 32);

    f32x4 acc0 = {0.f, 0.f, 0.f, 0.f}, acc1 = {0.f, 0.f, 0.f, 0.f};
    f32x4 acc2 = {0.f, 0.f, 0.f, 0.f}, acc3 = {0.f, 0.f, 0.f, 0.f};
    f32x4 acc4 = {0.f, 0.f, 0.f, 0.f};
#pragma unroll
    for (int kk = 0; kk < 16; kk++) {
      const int kbyte = (kk * 32 + kg * 8) * 2;
      bf16x8 b0 = *(const bf16x8*)((const char*)wlds + q * 1024 + (kbyte ^ sw));
      bf16x8 b1 =
          *(const bf16x8*)((const char*)wlds + (16 + q) * 1024 + (kbyte ^ sw));
      bf16x8 b2 =
          *(const bf16x8*)((const char*)wlds + (32 + q) * 1024 + (kbyte ^ sw));
      bf16x8 b3 =
          *(const bf16x8*)((const char*)wlds + (48 + q) * 1024 + (kbyte ^ sw));
      bf16x8 b4 =
          *(const bf16x8*)((const char*)wlds + (64 + q) * 1024 + (kbyte ^ sw));
      acc0 = __builtin_amdgcn_mfma_f32_16x16x32_bf16(ah[kk], b0, acc0, 0, 0, 0);
      acc1 = __builtin_amdgcn_mfma_f32_16x16x32_bf16(ah[kk], b1, acc1, 0, 0, 0);
      acc2 = __builtin_amdgcn_mfma_f32_16x16x32_bf16(ah[kk], b2, acc2, 0, 0, 0);
      acc3 = __builtin_amdgcn_mfma_f32_16x16x32_bf16(ax[kk], b3, acc3, 0, 0, 0);
      acc4 = __builtin_amdgcn_mfma_f32_16x16x32_bf16(ax[kk], b4, acc4, 0, 0, 0);
    }
    float ab0[4], ab1[4], ab2[4], ab3[4], ab4[4];
#pragma unroll
    for (int r = 0; r < 4; r++) {
      ab0[r] = acc0[r] + biasv[0];  // lo: gh_r   hi: gh_z
      ab1[r] = acc1[r] + biasv[1];  // lo: gh_n   hi: c
      ab2[r] = acc2[r] + biasv[2];  // lo: s      hi: t
      ab3[r] = acc3[r] + biasv[3];  // lo: gi_r   hi: gi_z
      ab4[r] = acc4[r] + biasv[4];  // lo: gi_n   hi: unused
    }
    float ghz[4], tv[4], giz[4], ec_sh[4];
#pragma unroll
    for (int r = 0; r < 4; r++) {
      ghz[r] = __shfl_xor(ab0[r], 8, 64);
      tv[r] = __shfl_xor(ab2[r], 8, 64);
      giz[r] = __shfl_xor(ab3[r], 8, 64);
      ec_sh[r] = __shfl_xor(ecp[r], 8, 64);  // e(c) from previous superstep
    }
    const int tt = it - 1;
    if (lo) {
#pragma unroll
      for (int r = 0; r < 4; r++) {
        const int b = browbase + r;
        if (it >= 1) {
          const float es = efun(ab2[r]);
          float* op = out + (size_t)b * (kT * kC) + (size_t)tt * kC +
                      (isA ? 0 : kD) + d;
          if (isA) {
            const float yv = es * xopf[r] + tv[r];  // y1 = e(s2v)*x1 + t2
            st_f32_wt(op, yv * ec_sh[r]);           // y1o = y1 * e(c2)
            st_b16_wt(y1buf + ((size_t)tt * 64 + b) * 512 + d, f2b(yv));
          } else {
            st_f32_wt(op, es * (xopf[r] * ec_sh[r]) + tv[r]);  // y2
          }
        }
        if (it <= 511) {
          const float rr = sigm(ab3[r] + ab0[r]);
          const float zz = sigm(giz[r] + ghz[r]);
          const float nn = tanh_(ab4[r] + rr * ab1[r]);
          const float hn = (1.f - zz) * nn + zz * hsl[r];
          hsl[r] = hn;
          st_b16_wt(hbuf + (size_t)(it + 1) * 32768 + (size_t)b * 512 + d,
                    f2b(hn));
        }
      }
    } else {
#pragma unroll
      for (int r = 0; r < 4; r++) ecp[r] = efun(ab1[r]);  // e(c(it))
    }

    // ---- arrival: drain write-through stores, then one flag store (own line)
    asm volatile("s_waitcnt vmcnt(0)" ::: "memory");
    __syncthreads();
    if (tid == 0)
      __hip_atomic_store(myflag, (unsigned)(s + 1), __ATOMIC_RELAXED,
                         __HIP_MEMORY_SCOPE_AGENT);
  }
}

extern "C" void kernel_launch(void* const* d_in, const int* in_sizes, int n_in,
                              void* d_out, int out_size, void* d_ws, size_t ws_size,
                              hipStream_t stream) {
  (void)in_sizes; (void)n_in; (void)out_size; (void)ws_size;
  const float* x = (const float*)d_in[0];
  const float* s1_Wih = (const float*)d_in[1];
  const float* s1_Whh = (const float*)d_in[2];
  const float* s1_bih = (const float*)d_in[3];
  const float* s1_bhh = (const float*)d_in[4];
  const float* s1_Wo = (const float*)d_in[5];
  const float* s1_bo = (const float*)d_in[6];
  const float* s2_Wih = (const float*)d_in[7];
  const float* s2_Whh = (const float*)d_in[8];
  const float* s2_bih = (const float*)d_in[9];
  const float* s2_bhh = (const float*)d_in[10];
  const float* s2_Wo = (const float*)d_in[11];
  const float* s2_bo = (const float*)d_in[12];
  const float* cg1_W = (const float*)d_in[13];
  const float* cg1_b = (const float*)d_in[14];
  const float* cg2_W = (const float*)d_in[15];
  const float* cg2_b = (const float*)d_in[16];
  float* out = (float*)d_out;
  char* ws = (char*)d_ws;

  // ws layout (bytes):
  //   xb2   @ 0          : T*B*512 bf16   = 33,554,432
  //   y1    @ 33554432   : T*B*512 bf16   = 33,554,432
  //   hbA   @ 67108864   : 513*B*512 bf16 = 33,619,968
  //   hbB   @ 100728832  : 33,619,968
  //   flags @ 134348800  : flagsA[64*32 u32]=8KB, flagsB +8KB
  unsigned short* xb2 = (unsigned short*)ws;
  unsigned short* y1b = (unsigned short*)(ws + 33554432);
  unsigned short* hbA = (unsigned short*)(ws + 67108864);
  unsigned short* hbB = (unsigned short*)(ws + 100728832);
  unsigned int* flagsA = (unsigned int*)(ws + 134348800);
  unsigned int* flagsB = (unsigned int*)(ws + 134348800 + 8192);

  // zero: h slot 0 for both chains + flags
  hipMemsetAsync(ws + 67108864, 0, 65536, stream);
  hipMemsetAsync(ws + 100728832, 0, 65536, stream);
  hipMemsetAsync(ws + 134348800, 0, 16384, stream);

  cvt_x2_kernel<<<8192, 256, 0, stream>>>(x, xb2);

  fused_glow_kernel<<<128, 256, 0, stream>>>(
      x, xb2,
      // chain A = s2 + cg2
      s2_Wih, s2_Whh, s2_bih, s2_bhh, s2_Wo, s2_bo, cg2_W, cg2_b,
      // chain B = s1 + cg1
      s1_Wih, s1_Whh, s1_bih, s1_bhh, s1_Wo, s1_bo, cg1_W, cg1_b,
      y1b, out, hbA, hbB, flagsA, flagsB);
}